// Round 3
// baseline (21827.921 us; speedup 1.0000x reference)
//
#include <hip/hip_runtime.h>
#include <math.h>

#define TC 64       // time chunk length
#define NCHUNK 8    // 512 / TC
#define GRP 32u     // workgroups per barrier group (same bb)

// ---------------- math helpers ----------------
__device__ __forceinline__ float sigmoidf_(float x) { return 1.0f / (1.0f + __expf(-x)); }
__device__ __forceinline__ float tanhf_(float x) {
    float e = __expf(2.0f * x);
    return 1.0f - 2.0f / (e + 1.0f);
}

// ---------------- per-group device barrier (32 participants) ----------------
// gbar -> {cnt, gen} in this group's private cacheline. agent-scope acq/rel
// handles cross-XCD L2 per Guideline 16. Guard breaks spin -> visible absmax
// failure instead of queue-timeout abort.
__device__ __forceinline__ void group_sync(unsigned* gbar) {
    __syncthreads();
    if (threadIdx.x == 0) {
        unsigned my = __hip_atomic_load(gbar + 1, __ATOMIC_RELAXED, __HIP_MEMORY_SCOPE_AGENT);
        unsigned a = __hip_atomic_fetch_add(gbar, 1u, __ATOMIC_ACQ_REL, __HIP_MEMORY_SCOPE_AGENT);
        if (a == GRP - 1u) {
            __hip_atomic_store(gbar, 0u, __ATOMIC_RELAXED, __HIP_MEMORY_SCOPE_AGENT);
            __hip_atomic_fetch_add(gbar + 1, 1u, __ATOMIC_RELEASE, __HIP_MEMORY_SCOPE_AGENT);
        } else {
            int guard = 0;
            while (__hip_atomic_load(gbar + 1, __ATOMIC_ACQUIRE, __HIP_MEMORY_SCOPE_AGENT) == my) {
                __builtin_amdgcn_s_sleep(2);
                if (++guard > (1 << 22)) break;  // failsafe
            }
        }
    }
    __syncthreads();
}

// ---------------- bias prep: bs = b_ih + b_hh ----------------
__global__ __launch_bounds__(256) void prep_bias(
    const float* __restrict__ bi0, const float* __restrict__ bh0,
    const float* __restrict__ bi1, const float* __restrict__ bh1,
    float* __restrict__ bs0, float* __restrict__ bs1) {
    int i = blockIdx.x * 256 + threadIdx.x;
    if (i < 2048) {
        bs0[i] = bi0[i] + bh0[i];
        bs1[i] = bi1[i] + bh1[i];
    }
}

// ---------------- carry init: copy h0/c0 per layer ----------------
__global__ __launch_bounds__(256) void init_carry(
    const float* __restrict__ h0, const float* __restrict__ c0,
    float* __restrict__ hc0, float* __restrict__ cc0,
    float* __restrict__ hc1, float* __restrict__ cc1) {
    int i = blockIdx.x * 256 + threadIdx.x;
    if (i < 32768) {
        hc0[i] = h0[i];
        cc0[i] = c0[i];
        hc1[i] = h0[32768 + i];
        cc1[i] = c0[32768 + i];
    }
}

// ---------------- chunk GEMM: out[outr][n] = sum_k A[arow][k]*Bw[n][k] + bias[n]
// 4096 rows (one chunk: 64 t x 64 b), 2048 cols. Bw: [2048][K].
// mode 0 (layer-0): r = b*TC + t  -> arow = b*512 + t0 + t, outr = t*64 + b
// mode 1 (layer-1): arow = r (rows already [t][b]), outr = r
template <int K>
__global__ __launch_bounds__(256) void gemm_xw(
    const float* __restrict__ A, const float* __restrict__ Bw,
    const float* __restrict__ bias, float* __restrict__ out,
    const int mode, const int t0) {
    __shared__ float As[16][128];
    __shared__ float Bs[16][128];
    const int tid = threadIdx.x;
    const int bm = blockIdx.y, bn = blockIdx.x;
    const int lrow = tid >> 1;      // 0..127
    const int lk0 = (tid & 1) * 8;  // 0 or 8
    const int grow = bm * 128 + lrow;
    const int arow = mode ? grow : ((grow >> 6) * 512 + t0 + (grow & 63));
    const float* Ap = A + (size_t)arow * K + lk0;
    const float* Bp = Bw + (size_t)(bn * 128 + lrow) * K + lk0;
    const int ty = tid >> 4, tx = tid & 15;

    float acc[8][8];
#pragma unroll
    for (int i = 0; i < 8; ++i)
#pragma unroll
        for (int j = 0; j < 8; ++j) acc[i][j] = 0.f;

    float4 pa0 = *(const float4*)(Ap);
    float4 pa1 = *(const float4*)(Ap + 4);
    float4 pb0 = *(const float4*)(Bp);
    float4 pb1 = *(const float4*)(Bp + 4);

    const int NT = K / 16;
    for (int ktile = 0; ktile < NT; ++ktile) {
#pragma unroll
        for (int c = 0; c < 4; ++c) {
            As[lk0 + c][lrow] = ((float*)&pa0)[c];
            As[lk0 + 4 + c][lrow] = ((float*)&pa1)[c];
            Bs[lk0 + c][lrow] = ((float*)&pb0)[c];
            Bs[lk0 + 4 + c][lrow] = ((float*)&pb1)[c];
        }
        __syncthreads();
        if (ktile + 1 < NT) {
            const float* Apn = Ap + (ktile + 1) * 16;
            const float* Bpn = Bp + (ktile + 1) * 16;
            pa0 = *(const float4*)(Apn);
            pa1 = *(const float4*)(Apn + 4);
            pb0 = *(const float4*)(Bpn);
            pb1 = *(const float4*)(Bpn + 4);
        }
#pragma unroll
        for (int kk = 0; kk < 16; ++kk) {
            const float4 a0 = *(const float4*)&As[kk][ty * 8];
            const float4 a1 = *(const float4*)&As[kk][ty * 8 + 4];
            const float4 b0 = *(const float4*)&Bs[kk][tx * 8];
            const float4 b1 = *(const float4*)&Bs[kk][tx * 8 + 4];
            const float av[8] = {a0.x, a0.y, a0.z, a0.w, a1.x, a1.y, a1.z, a1.w};
            const float bv[8] = {b0.x, b0.y, b0.z, b0.w, b1.x, b1.y, b1.z, b1.w};
#pragma unroll
            for (int i = 0; i < 8; ++i)
#pragma unroll
                for (int j = 0; j < 8; ++j) acc[i][j] = fmaf(av[i], bv[j], acc[i][j]);
        }
        __syncthreads();
    }

    const int col0 = bn * 128 + tx * 8;
    const float4 bv0 = *(const float4*)&bias[col0];
    const float4 bv1 = *(const float4*)&bias[col0 + 4];
    const float bb[8] = {bv0.x, bv0.y, bv0.z, bv0.w, bv1.x, bv1.y, bv1.z, bv1.w};
#pragma unroll
    for (int i = 0; i < 8; ++i) {
        int gr = bm * 128 + ty * 8 + i;
        int outr = mode ? gr : ((gr & 63) * 64 + (gr >> 6));
        float* op = out + (size_t)outr * 2048 + col0;
#pragma unroll
        for (int j = 0; j < 8; ++j) op[j] = acc[i][j] + bb[j];
    }
}

// ---------------- persistent LSTM recurrence over one TC chunk ----------------
// 256 WGs x 256 threads, 1 WG/CU (147 KB LDS). WG: jb = bid>>3 (16 j's),
// bb = bid&7 (8 batches). Barrier group = 32 WGs sharing bb.
// hcar/ccar: [64][512] carries (read at t=0, rewritten at t=TC-1).
// hbuf: full_seq ? [TC+1][64][512] : [2][64][512] ping-pong.
__global__ __launch_bounds__(256, 1) void lstm_rec(
    const float* __restrict__ xW,   // [TC][64][2048]
    const float* __restrict__ Whh,  // [2048][512]
    float* hcar, float* ccar,
    float* __restrict__ hbuf, const int full_seq, unsigned* bars) {
    __shared__ float W4[16 * 512 * 4];  // 131072 B
    __shared__ float h4[8 * 512];       // 16384 B
    const int tid = threadIdx.x;
    const int jb = blockIdx.x >> 3;
    const int bb = blockIdx.x & 7;
    const int jt = tid >> 5, kt = tid & 31;
    unsigned* gbar = bars + bb * 32;  // 128 B per group

    // load W_hh slice into LDS once: layout [j][k][gate], f4-slot XOR swizzle
    for (int i = 0; i < 32; ++i) {
        int fid = tid + i * 256;
        int k4 = fid & 127, rest = fid >> 7;
        int g = rest & 3, j = rest >> 2;
        const float4 v = *(const float4*)&Whh[(size_t)(g * 512 + jb * 16 + j) * 512 + k4 * 4];
#pragma unroll
        for (int c = 0; c < 4; ++c) {
            int slot = j * 512 + k4 * 4 + c;
            int phys = slot ^ ((slot >> 4) & 7);
            W4[phys * 4 + g] = ((const float*)&v)[c];
        }
    }

    // cell owned by this lane after reduction
    const int jj_c = (kt >> 4) & 1;
    const int bl_c = (kt >> 1) & 7;
    const int j_cell = jb * 16 + jt * 2 + jj_c;
    const int b_cell = bb * 8 + bl_c;

    float c = ccar[b_cell * 512 + j_cell];
    if ((kt & 1) == 0) hbuf[b_cell * 512 + j_cell] = hcar[b_cell * 512 + j_cell];  // slot 0

    group_sync(gbar);  // also covers the W4 __syncthreads

    for (int t = 0; t < TC; ++t) {
        const int rd = full_seq ? t : (t & 1);
        const int wr = full_seq ? (t + 1) : ((t + 1) & 1);
        const float* hrd = hbuf + (size_t)rd * 32768;

        // this cell's xW (4 gates)
        const float* xwp = xW + (size_t)t * 131072 + b_cell * 2048 + j_cell;
        const float xw0 = xwp[0], xw1 = xwp[512], xw2 = xwp[1024], xw3 = xwp[1536];

        // stage h tile into LDS ([b][k], f4-slot swizzled)
#pragma unroll
        for (int i = 0; i < 4; ++i) {
            int fid = tid + i * 256;
            int b = fid >> 7, k4 = fid & 127;
            float4 v = *(const float4*)&hrd[(bb * 8 + b) * 512 + k4 * 4];
            int slot = b * 128 + k4;
            int phys = slot ^ ((slot >> 4) & 7);
            *(float4*)&h4[phys * 4] = v;
        }
        __syncthreads();

        float acc[2][4][8];  // [jj][gate][b]
#pragma unroll
        for (int jj = 0; jj < 2; ++jj)
#pragma unroll
            for (int g = 0; g < 4; ++g)
#pragma unroll
                for (int b = 0; b < 8; ++b) acc[jj][g][b] = 0.f;

#pragma unroll
        for (int kk4 = 0; kk4 < 4; ++kk4) {
            const int k4 = kt * 4 + kk4;
            float4 hv[8];
#pragma unroll
            for (int b = 0; b < 8; ++b) {
                int slot = b * 128 + k4;
                hv[b] = *(const float4*)&h4[(slot ^ ((slot >> 4) & 7)) * 4];
            }
#pragma unroll
            for (int jj = 0; jj < 2; ++jj) {
#pragma unroll
                for (int kc = 0; kc < 4; ++kc) {
                    const int slot = (jt * 2 + jj) * 512 + k4 * 4 + kc;
                    const float4 wv = *(const float4*)&W4[(slot ^ ((slot >> 4) & 7)) * 4];
#pragma unroll
                    for (int b = 0; b < 8; ++b) {
                        const float hb = ((const float*)&hv[b])[kc];
                        acc[jj][0][b] = fmaf(wv.x, hb, acc[jj][0][b]);
                        acc[jj][1][b] = fmaf(wv.y, hb, acc[jj][1][b]);
                        acc[jj][2][b] = fmaf(wv.z, hb, acc[jj][2][b]);
                        acc[jj][3][b] = fmaf(wv.w, hb, acc[jj][3][b]);
                    }
                }
            }
        }

        // merge-exchange reduction over the 32-way k-split
        float m32[4][8];
#pragma unroll
        for (int g = 0; g < 4; ++g)
#pragma unroll
            for (int b = 0; b < 8; ++b) {
                float keep = (kt & 16) ? acc[1][g][b] : acc[0][g][b];
                float send = (kt & 16) ? acc[0][g][b] : acc[1][g][b];
                m32[g][b] = keep + __shfl_xor(send, 16);
            }
        float m16[4][4];
#pragma unroll
        for (int g = 0; g < 4; ++g)
#pragma unroll
            for (int b = 0; b < 4; ++b) {
                float keep = (kt & 8) ? m32[g][b + 4] : m32[g][b];
                float send = (kt & 8) ? m32[g][b] : m32[g][b + 4];
                m16[g][b] = keep + __shfl_xor(send, 8);
            }
        float m8[4][2];
#pragma unroll
        for (int g = 0; g < 4; ++g)
#pragma unroll
            for (int b = 0; b < 2; ++b) {
                float keep = (kt & 4) ? m16[g][b + 2] : m16[g][b];
                float send = (kt & 4) ? m16[g][b] : m16[g][b + 2];
                m8[g][b] = keep + __shfl_xor(send, 4);
            }
        float s[4];
#pragma unroll
        for (int g = 0; g < 4; ++g) {
            float keep = (kt & 2) ? m8[g][1] : m8[g][0];
            float send = (kt & 2) ? m8[g][0] : m8[g][1];
            float m = keep + __shfl_xor(send, 2);
            s[g] = m + __shfl_xor(m, 1);
        }

        // gates + state update
        const float gi = sigmoidf_(s[0] + xw0);
        const float gf = sigmoidf_(s[1] + xw1);
        const float gg = tanhf_(s[2] + xw2);
        const float go = sigmoidf_(s[3] + xw3);
        c = gf * c + gi * gg;
        const float hn = go * tanhf_(c);
        if ((kt & 1) == 0) {
            hbuf[(size_t)wr * 32768 + b_cell * 512 + j_cell] = hn;
            if (t == TC - 1) {  // write carries for next chunk
                hcar[b_cell * 512 + j_cell] = hn;
                ccar[b_cell * 512 + j_cell] = c;
            }
        }

        group_sync(gbar);
    }
}

// ---------------- FC head ----------------
__global__ __launch_bounds__(256) void fc_kernel(
    const float* __restrict__ h, const float* __restrict__ Wfc,
    const float* __restrict__ bfc, float* __restrict__ out) {
    int gid = blockIdx.x * 256 + threadIdx.x;  // 0..8191
    int b = gid >> 7, cc = gid & 127;
    const float* hr = h + b * 512;
    const float* wr = Wfc + cc * 512;
    float s = 0.f;
#pragma unroll 4
    for (int k = 0; k < 512; k += 4) {
        float4 hv = *(const float4*)(hr + k);
        float4 wv = *(const float4*)(wr + k);
        s += hv.x * wv.x + hv.y * wv.y + hv.z * wv.z + hv.w * wv.w;
    }
    out[gid] = s + bfc[cc];
}

// ---------------- launch ----------------
extern "C" void kernel_launch(void* const* d_in, const int* in_sizes, int n_in,
                              void* d_out, int out_size, void* d_ws, size_t ws_size,
                              hipStream_t stream) {
    const float* x = (const float*)d_in[0];
    const float* h0 = (const float*)d_in[1];
    const float* c0 = (const float*)d_in[2];
    const float* Wih0 = (const float*)d_in[3];
    const float* Whh0 = (const float*)d_in[4];
    const float* bih0 = (const float*)d_in[5];
    const float* bhh0 = (const float*)d_in[6];
    const float* Wih1 = (const float*)d_in[7];
    const float* Whh1 = (const float*)d_in[8];
    const float* bih1 = (const float*)d_in[9];
    const float* bhh1 = (const float*)d_in[10];
    const float* Wfc = (const float*)d_in[11];
    const float* bfc = (const float*)d_in[12];

    // workspace layout (~43 MB total)
    char* ws = (char*)d_ws;
    size_t off = 0;
    float* xWc = (float*)(ws + off); off += (size_t)TC * 64 * 2048 * 4;      // 33,554,432
    float* hseqc = (float*)(ws + off); off += (size_t)(TC + 1) * 32768 * 4;  //  8,519,680
    float* hpp = (float*)(ws + off); off += 2 * 32768 * 4;                   //    262,144
    float* hcar0 = (float*)(ws + off); off += 32768 * 4;
    float* ccar0 = (float*)(ws + off); off += 32768 * 4;
    float* hcar1 = (float*)(ws + off); off += 32768 * 4;
    float* ccar1 = (float*)(ws + off); off += 32768 * 4;
    float* bs0 = (float*)(ws + off); off += 2048 * 4;
    float* bs1 = (float*)(ws + off); off += 2048 * 4;
    unsigned* bars = (unsigned*)(ws + off); off += 8 * 32 * 4;

    prep_bias<<<8, 256, 0, stream>>>(bih0, bhh0, bih1, bhh1, bs0, bs1);
    init_carry<<<128, 256, 0, stream>>>(h0, c0, hcar0, ccar0, hcar1, ccar1);
    hipMemsetAsync(bars, 0, 8 * 32 * 4, stream);

    const dim3 gg(16, 32);
    for (int k = 0; k < NCHUNK; ++k) {
        // layer-0 input GEMM for chunk k: xWc[t][b][2048]
        gemm_xw<256><<<gg, 256, 0, stream>>>(x, Wih0, bs0, xWc, 0, k * TC);
        // layer-0 recurrence over chunk; writes hseqc slots 1..TC
        lstm_rec<<<256, 256, 0, stream>>>(xWc, Whh0, hcar0, ccar0, hseqc, 1, bars);
        // layer-1 input GEMM from hseqc slots 1..TC (rows already [t][b])
        gemm_xw<512><<<gg, 256, 0, stream>>>(hseqc + 32768, Wih1, bs1, xWc, 1, 0);
        // layer-1 recurrence (ping-pong h)
        lstm_rec<<<256, 256, 0, stream>>>(xWc, Whh1, hcar1, ccar1, hpp, 0, bars);
    }
    // FC on final layer-1 hidden state (carry buffer)
    fc_kernel<<<32, 256, 0, stream>>>(hcar1, Wfc, bfc, (float*)d_out);
}

// Round 4
// 10355.034 us; speedup vs baseline: 2.1080x; 2.1080x over previous
//
#include <hip/hip_runtime.h>
#include <math.h>

#define TC 64       // time chunk length
#define NCHUNK 8    // 512 / TC

// ---------------- math helpers ----------------
__device__ __forceinline__ float sigmoidf_(float x) { return 1.0f / (1.0f + __expf(-x)); }
__device__ __forceinline__ float tanhf_(float x) {
    float e = __expf(2.0f * x);
    return 1.0f - 2.0f / (e + 1.0f);
}

// relaxed agent-scope accessors (compile to sc1 cache-bypassing ops, coherent at LLC)
__device__ __forceinline__ void st_agent_f32(float* p, float v) {
    __hip_atomic_store(p, v, __ATOMIC_RELAXED, __HIP_MEMORY_SCOPE_AGENT);
}
__device__ __forceinline__ unsigned long long ld_agent_u64(const unsigned long long* p) {
    return __hip_atomic_load(p, __ATOMIC_RELAXED, __HIP_MEMORY_SCOPE_AGENT);
}
__device__ __forceinline__ void st_agent_u32(unsigned* p, unsigned v) {
    __hip_atomic_store(p, v, __ATOMIC_RELAXED, __HIP_MEMORY_SCOPE_AGENT);
}
__device__ __forceinline__ unsigned ld_agent_u32(const unsigned* p) {
    return __hip_atomic_load(p, __ATOMIC_RELAXED, __HIP_MEMORY_SCOPE_AGENT);
}

// ---------------- bias prep: bs = b_ih + b_hh ----------------
__global__ __launch_bounds__(256) void prep_bias(
    const float* __restrict__ bi0, const float* __restrict__ bh0,
    const float* __restrict__ bi1, const float* __restrict__ bh1,
    float* __restrict__ bs0, float* __restrict__ bs1) {
    int i = blockIdx.x * 256 + threadIdx.x;
    if (i < 2048) {
        bs0[i] = bi0[i] + bh0[i];
        bs1[i] = bi1[i] + bh1[i];
    }
}

// ---------------- carry init: copy h0/c0 per layer ----------------
__global__ __launch_bounds__(256) void init_carry(
    const float* __restrict__ h0, const float* __restrict__ c0,
    float* __restrict__ hc0, float* __restrict__ cc0,
    float* __restrict__ hc1, float* __restrict__ cc1) {
    int i = blockIdx.x * 256 + threadIdx.x;
    if (i < 32768) {
        hc0[i] = h0[i];
        cc0[i] = c0[i];
        hc1[i] = h0[32768 + i];
        cc1[i] = c0[32768 + i];
    }
}

// ---------------- chunk GEMM: out[outr][n] = sum_k A[arow][k]*Bw[n][k] + bias[n]
// 4096 rows (one chunk: 64 t x 64 b), 2048 cols. Bw: [2048][K].
// mode 0 (layer-0): r = b*TC + t  -> arow = b*512 + t0 + t, outr = t*64 + b
// mode 1 (layer-1): arow = r (rows already [t][b]), outr = r
template <int K>
__global__ __launch_bounds__(256) void gemm_xw(
    const float* __restrict__ A, const float* __restrict__ Bw,
    const float* __restrict__ bias, float* __restrict__ out,
    const int mode, const int t0) {
    __shared__ float As[16][128];
    __shared__ float Bs[16][128];
    const int tid = threadIdx.x;
    const int bm = blockIdx.y, bn = blockIdx.x;
    const int lrow = tid >> 1;      // 0..127
    const int lk0 = (tid & 1) * 8;  // 0 or 8
    const int grow = bm * 128 + lrow;
    const int arow = mode ? grow : ((grow >> 6) * 512 + t0 + (grow & 63));
    const float* Ap = A + (size_t)arow * K + lk0;
    const float* Bp = Bw + (size_t)(bn * 128 + lrow) * K + lk0;
    const int ty = tid >> 4, tx = tid & 15;

    float acc[8][8];
#pragma unroll
    for (int i = 0; i < 8; ++i)
#pragma unroll
        for (int j = 0; j < 8; ++j) acc[i][j] = 0.f;

    float4 pa0 = *(const float4*)(Ap);
    float4 pa1 = *(const float4*)(Ap + 4);
    float4 pb0 = *(const float4*)(Bp);
    float4 pb1 = *(const float4*)(Bp + 4);

    const int NT = K / 16;
    for (int ktile = 0; ktile < NT; ++ktile) {
#pragma unroll
        for (int c = 0; c < 4; ++c) {
            As[lk0 + c][lrow] = ((float*)&pa0)[c];
            As[lk0 + 4 + c][lrow] = ((float*)&pa1)[c];
            Bs[lk0 + c][lrow] = ((float*)&pb0)[c];
            Bs[lk0 + 4 + c][lrow] = ((float*)&pb1)[c];
        }
        __syncthreads();
        if (ktile + 1 < NT) {
            const float* Apn = Ap + (ktile + 1) * 16;
            const float* Bpn = Bp + (ktile + 1) * 16;
            pa0 = *(const float4*)(Apn);
            pa1 = *(const float4*)(Apn + 4);
            pb0 = *(const float4*)(Bpn);
            pb1 = *(const float4*)(Bpn + 4);
        }
#pragma unroll
        for (int kk = 0; kk < 16; ++kk) {
            const float4 a0 = *(const float4*)&As[kk][ty * 8];
            const float4 a1 = *(const float4*)&As[kk][ty * 8 + 4];
            const float4 b0 = *(const float4*)&Bs[kk][tx * 8];
            const float4 b1 = *(const float4*)&Bs[kk][tx * 8 + 4];
            const float av[8] = {a0.x, a0.y, a0.z, a0.w, a1.x, a1.y, a1.z, a1.w};
            const float bv[8] = {b0.x, b0.y, b0.z, b0.w, b1.x, b1.y, b1.z, b1.w};
#pragma unroll
            for (int i = 0; i < 8; ++i)
#pragma unroll
                for (int j = 0; j < 8; ++j) acc[i][j] = fmaf(av[i], bv[j], acc[i][j]);
        }
        __syncthreads();
    }

    const int col0 = bn * 128 + tx * 8;
    const float4 bv0 = *(const float4*)&bias[col0];
    const float4 bv1 = *(const float4*)&bias[col0 + 4];
    const float bb[8] = {bv0.x, bv0.y, bv0.z, bv0.w, bv1.x, bv1.y, bv1.z, bv1.w};
#pragma unroll
    for (int i = 0; i < 8; ++i) {
        int gr = bm * 128 + ty * 8 + i;
        int outr = mode ? gr : ((gr & 63) * 64 + (gr >> 6));
        float* op = out + (size_t)outr * 2048 + col0;
#pragma unroll
        for (int j = 0; j < 8; ++j) op[j] = acc[i][j] + bb[j];
    }
}

// ---------------- persistent LSTM recurrence over one TC chunk ----------------
// 256 WGs x 256 threads, 1 WG/CU (147 KB LDS). WG: jb = bid>>3 (16 j's),
// bb = bid&7 (8 batches). Sync group = 32 WGs sharing bb.
// Fence-free sync: producer __syncthreads (drains sc1 h-stores) -> relaxed
// agent flag store; consumers poll 32 group flags with relaxed agent loads.
// All cross-WG h traffic is relaxed agent-scope (sc1, LLC-coherent).
// flags monotonic: target = fbase + t + 1; no barrier after last step.
__global__ __launch_bounds__(256, 1) void lstm_rec(
    const float* __restrict__ xW,   // [TC][64][2048]
    const float* __restrict__ Whh,  // [2048][512]
    float* hcar, float* ccar,
    float* hbuf, const int full_seq, unsigned* flags, const int fbase) {
    __shared__ float W4[16 * 512 * 4];  // 131072 B
    __shared__ float h4[8 * 512];       // 16384 B
    const int tid = threadIdx.x;
    const int jb = blockIdx.x >> 3;
    const int bb = blockIdx.x & 7;
    const int jt = tid >> 5, kt = tid & 31;
    unsigned* gflags = flags + bb * 32;  // 128 B per group

    // load W_hh slice into LDS once: layout [j][k][gate], f4-slot XOR swizzle
    for (int i = 0; i < 32; ++i) {
        int fid = tid + i * 256;
        int k4 = fid & 127, rest = fid >> 7;
        int g = rest & 3, j = rest >> 2;
        const float4 v = *(const float4*)&Whh[(size_t)(g * 512 + jb * 16 + j) * 512 + k4 * 4];
#pragma unroll
        for (int c = 0; c < 4; ++c) {
            int slot = j * 512 + k4 * 4 + c;
            int phys = slot ^ ((slot >> 4) & 7);
            W4[phys * 4 + g] = ((const float*)&v)[c];
        }
    }

    // cell owned by this lane after reduction
    const int jj_c = (kt >> 4) & 1;
    const int bl_c = (kt >> 1) & 7;
    const int j_cell = jb * 16 + jt * 2 + jj_c;
    const int b_cell = bb * 8 + bl_c;

    float c = ccar[b_cell * 512 + j_cell];
    if ((kt & 1) == 0)
        st_agent_f32(&hbuf[b_cell * 512 + j_cell], hcar[b_cell * 512 + j_cell]);  // slot 0

    // prefetch xW for t=0 (plain loads; xW written by a previous dispatch)
    const float* xwp0 = xW + b_cell * 2048 + j_cell;
    float xw0 = xwp0[0], xw1 = xwp0[512], xw2 = xwp0[1024], xw3 = xwp0[1536];

    // ---- barrier 0: publish slot-0 h (and cover W4 LDS writes) ----
    __syncthreads();  // drains vmcnt (sc1 stores at LLC) + lgkmcnt
    if (tid == 0) st_agent_u32(&gflags[jb], (unsigned)(fbase + 1));
    if (tid < 64) {
        const unsigned tgt = (unsigned)(fbase + 1);
        int guard = 0;
        for (;;) {
            unsigned v = ld_agent_u32(&gflags[tid & 31]);
            if (__all((int)(v >= tgt))) break;
            __builtin_amdgcn_s_sleep(2);
            if (++guard > (1 << 18)) break;  // failsafe -> visible absmax failure
        }
    }
    __syncthreads();

    for (int t = 0; t < TC; ++t) {
        const int rd = full_seq ? t : (t & 1);
        const int wr = full_seq ? (t + 1) : ((t + 1) & 1);
        const float* hrd = hbuf + (size_t)rd * 32768;

        // stage h tile into LDS via sc1 8B loads ([b][k], f4-slot swizzled)
#pragma unroll
        for (int i = 0; i < 8; ++i) {
            int fid = tid + i * 256;  // 0..2047 (2048 8B slots)
            int b = fid >> 8, k2 = fid & 255;
            unsigned long long v =
                ld_agent_u64((const unsigned long long*)&hrd[(bb * 8 + b) * 512 + k2 * 2]);
            int slot4 = b * 128 + (k2 >> 1);
            int phys = slot4 ^ ((slot4 >> 4) & 7);
            *(unsigned long long*)&h4[phys * 4 + (k2 & 1) * 2] = v;
        }
        __syncthreads();

        float acc[2][4][8];  // [jj][gate][b]
#pragma unroll
        for (int jj = 0; jj < 2; ++jj)
#pragma unroll
            for (int g = 0; g < 4; ++g)
#pragma unroll
                for (int b = 0; b < 8; ++b) acc[jj][g][b] = 0.f;

#pragma unroll
        for (int kk4 = 0; kk4 < 4; ++kk4) {
            const int k4 = kt * 4 + kk4;
            float4 hv[8];
#pragma unroll
            for (int b = 0; b < 8; ++b) {
                int slot = b * 128 + k4;
                hv[b] = *(const float4*)&h4[(slot ^ ((slot >> 4) & 7)) * 4];
            }
#pragma unroll
            for (int jj = 0; jj < 2; ++jj) {
#pragma unroll
                for (int kc = 0; kc < 4; ++kc) {
                    const int slot = (jt * 2 + jj) * 512 + k4 * 4 + kc;
                    const float4 wv = *(const float4*)&W4[(slot ^ ((slot >> 4) & 7)) * 4];
#pragma unroll
                    for (int b = 0; b < 8; ++b) {
                        const float hb = ((const float*)&hv[b])[kc];
                        acc[jj][0][b] = fmaf(wv.x, hb, acc[jj][0][b]);
                        acc[jj][1][b] = fmaf(wv.y, hb, acc[jj][1][b]);
                        acc[jj][2][b] = fmaf(wv.z, hb, acc[jj][2][b]);
                        acc[jj][3][b] = fmaf(wv.w, hb, acc[jj][3][b]);
                    }
                }
            }
        }

        // merge-exchange reduction over the 32-way k-split
        float m32[4][8];
#pragma unroll
        for (int g = 0; g < 4; ++g)
#pragma unroll
            for (int b = 0; b < 8; ++b) {
                float keep = (kt & 16) ? acc[1][g][b] : acc[0][g][b];
                float send = (kt & 16) ? acc[0][g][b] : acc[1][g][b];
                m32[g][b] = keep + __shfl_xor(send, 16);
            }
        float m16[4][4];
#pragma unroll
        for (int g = 0; g < 4; ++g)
#pragma unroll
            for (int b = 0; b < 4; ++b) {
                float keep = (kt & 8) ? m32[g][b + 4] : m32[g][b];
                float send = (kt & 8) ? m32[g][b] : m32[g][b + 4];
                m16[g][b] = keep + __shfl_xor(send, 8);
            }
        float m8[4][2];
#pragma unroll
        for (int g = 0; g < 4; ++g)
#pragma unroll
            for (int b = 0; b < 2; ++b) {
                float keep = (kt & 4) ? m16[g][b + 2] : m16[g][b];
                float send = (kt & 4) ? m16[g][b] : m16[g][b + 2];
                m8[g][b] = keep + __shfl_xor(send, 4);
            }
        float s[4];
#pragma unroll
        for (int g = 0; g < 4; ++g) {
            float keep = (kt & 2) ? m8[g][1] : m8[g][0];
            float send = (kt & 2) ? m8[g][0] : m8[g][1];
            float m = keep + __shfl_xor(send, 2);
            s[g] = m + __shfl_xor(m, 1);
        }

        // gates + state update
        const float gi = sigmoidf_(s[0] + xw0);
        const float gf = sigmoidf_(s[1] + xw1);
        const float gg = tanhf_(s[2] + xw2);
        const float go = sigmoidf_(s[3] + xw3);
        c = gf * c + gi * gg;
        const float hn = go * tanhf_(c);
        if ((kt & 1) == 0) {
            st_agent_f32(&hbuf[(size_t)wr * 32768 + b_cell * 512 + j_cell], hn);
            if (t == TC - 1) {  // carries for next chunk (cross-dispatch: plain ok)
                hcar[b_cell * 512 + j_cell] = hn;
                ccar[b_cell * 512 + j_cell] = c;
            }
        }

        // prefetch next step's xW before the wait (hides LLC latency)
        if (t + 1 < TC) {
            const float* xwp = xW + (size_t)(t + 1) * 131072 + b_cell * 2048 + j_cell;
            xw0 = xwp[0];
            xw1 = xwp[512];
            xw2 = xwp[1024];
            xw3 = xwp[1536];
        }

        // ---- publish h(t+1) + wait for group (skip after last step) ----
        if (t < TC - 1) {
            __syncthreads();  // drains all waves' sc1 h-stores
            if (tid == 0) st_agent_u32(&gflags[jb], (unsigned)(fbase + t + 2));
            if (tid < 64) {
                const unsigned tgt = (unsigned)(fbase + t + 2);
                int guard = 0;
                for (;;) {
                    unsigned v = ld_agent_u32(&gflags[tid & 31]);
                    if (__all((int)(v >= tgt))) break;
                    __builtin_amdgcn_s_sleep(2);
                    if (++guard > (1 << 18)) break;  // failsafe
                }
            }
            __syncthreads();
        }
    }
}

// ---------------- FC head ----------------
__global__ __launch_bounds__(256) void fc_kernel(
    const float* __restrict__ h, const float* __restrict__ Wfc,
    const float* __restrict__ bfc, float* __restrict__ out) {
    int gid = blockIdx.x * 256 + threadIdx.x;  // 0..8191
    int b = gid >> 7, cc = gid & 127;
    const float* hr = h + b * 512;
    const float* wr = Wfc + cc * 512;
    float s = 0.f;
#pragma unroll 4
    for (int k = 0; k < 512; k += 4) {
        float4 hv = *(const float4*)(hr + k);
        float4 wv = *(const float4*)(wr + k);
        s += hv.x * wv.x + hv.y * wv.y + hv.z * wv.z + hv.w * wv.w;
    }
    out[gid] = s + bfc[cc];
}

// ---------------- launch ----------------
extern "C" void kernel_launch(void* const* d_in, const int* in_sizes, int n_in,
                              void* d_out, int out_size, void* d_ws, size_t ws_size,
                              hipStream_t stream) {
    const float* x = (const float*)d_in[0];
    const float* h0 = (const float*)d_in[1];
    const float* c0 = (const float*)d_in[2];
    const float* Wih0 = (const float*)d_in[3];
    const float* Whh0 = (const float*)d_in[4];
    const float* bih0 = (const float*)d_in[5];
    const float* bhh0 = (const float*)d_in[6];
    const float* Wih1 = (const float*)d_in[7];
    const float* Whh1 = (const float*)d_in[8];
    const float* bih1 = (const float*)d_in[9];
    const float* bhh1 = (const float*)d_in[10];
    const float* Wfc = (const float*)d_in[11];
    const float* bfc = (const float*)d_in[12];

    // workspace layout (~43 MB total)
    char* ws = (char*)d_ws;
    size_t off = 0;
    float* xWc = (float*)(ws + off); off += (size_t)TC * 64 * 2048 * 4;      // 33,554,432
    float* hseqc = (float*)(ws + off); off += (size_t)(TC + 1) * 32768 * 4;  //  8,519,680
    float* hpp = (float*)(ws + off); off += 2 * 32768 * 4;                   //    262,144
    float* hcar0 = (float*)(ws + off); off += 32768 * 4;
    float* ccar0 = (float*)(ws + off); off += 32768 * 4;
    float* hcar1 = (float*)(ws + off); off += 32768 * 4;
    float* ccar1 = (float*)(ws + off); off += 32768 * 4;
    float* bs0 = (float*)(ws + off); off += 2048 * 4;
    float* bs1 = (float*)(ws + off); off += 2048 * 4;
    unsigned* flagsA = (unsigned*)(ws + off); off += 256 * 4;  // layer-0 flags (8 grp x 32)
    unsigned* flagsB = (unsigned*)(ws + off); off += 256 * 4;  // layer-1 flags

    prep_bias<<<8, 256, 0, stream>>>(bih0, bhh0, bih1, bhh1, bs0, bs1);
    init_carry<<<128, 256, 0, stream>>>(h0, c0, hcar0, ccar0, hcar1, ccar1);
    hipMemsetAsync(flagsA, 0, 2 * 256 * 4, stream);

    const dim3 gg(16, 32);
    for (int k = 0; k < NCHUNK; ++k) {
        // layer-0 input GEMM for chunk k: xWc[t][b][2048]
        gemm_xw<256><<<gg, 256, 0, stream>>>(x, Wih0, bs0, xWc, 0, k * TC);
        // layer-0 recurrence over chunk; writes hseqc slots 1..TC
        lstm_rec<<<256, 256, 0, stream>>>(xWc, Whh0, hcar0, ccar0, hseqc, 1, flagsA, k * TC);
        // layer-1 input GEMM from hseqc slots 1..TC (rows already [t][b])
        gemm_xw<512><<<gg, 256, 0, stream>>>(hseqc + 32768, Wih1, bs1, xWc, 1, 0);
        // layer-1 recurrence (ping-pong h)
        lstm_rec<<<256, 256, 0, stream>>>(xWc, Whh1, hcar1, ccar1, hpp, 0, flagsB, k * TC);
    }
    // FC on final layer-1 hidden state (carry buffer)
    fc_kernel<<<32, 256, 0, stream>>>(hcar1, Wfc, bfc, (float*)d_out);
}

// Round 5
// 8915.425 us; speedup vs baseline: 2.4483x; 1.1615x over previous
//
#include <hip/hip_runtime.h>
#include <math.h>

#define TC 64       // time chunk length
#define NCHUNK 8    // 512 / TC
#define NGW 64      // workgroups per sync group (one per j-slice)

// ---------------- math helpers ----------------
__device__ __forceinline__ float sigmoidf_(float x) { return 1.0f / (1.0f + __expf(-x)); }
__device__ __forceinline__ float tanhf_(float x) {
    float e = __expf(2.0f * x);
    return 1.0f - 2.0f / (e + 1.0f);
}

// relaxed agent-scope accessors (sc1 cache-bypassing, coherent at LLC)
__device__ __forceinline__ void st_agent_f32(float* p, float v) {
    __hip_atomic_store(p, v, __ATOMIC_RELAXED, __HIP_MEMORY_SCOPE_AGENT);
}
__device__ __forceinline__ unsigned long long ld_agent_u64(const unsigned long long* p) {
    return __hip_atomic_load(p, __ATOMIC_RELAXED, __HIP_MEMORY_SCOPE_AGENT);
}
__device__ __forceinline__ void st_agent_u32(unsigned* p, unsigned v) {
    __hip_atomic_store(p, v, __ATOMIC_RELAXED, __HIP_MEMORY_SCOPE_AGENT);
}
__device__ __forceinline__ unsigned ld_agent_u32(const unsigned* p) {
    return __hip_atomic_load(p, __ATOMIC_RELAXED, __HIP_MEMORY_SCOPE_AGENT);
}

// ---------------- bias prep: bs = b_ih + b_hh ----------------
__global__ __launch_bounds__(256) void prep_bias(
    const float* __restrict__ bi0, const float* __restrict__ bh0,
    const float* __restrict__ bi1, const float* __restrict__ bh1,
    float* __restrict__ bs0, float* __restrict__ bs1) {
    int i = blockIdx.x * 256 + threadIdx.x;
    if (i < 2048) {
        bs0[i] = bi0[i] + bh0[i];
        bs1[i] = bi1[i] + bh1[i];
    }
}

// ---------------- carry init: copy h0/c0 per layer ----------------
__global__ __launch_bounds__(256) void init_carry(
    const float* __restrict__ h0, const float* __restrict__ c0,
    float* __restrict__ hc0, float* __restrict__ cc0,
    float* __restrict__ hc1, float* __restrict__ cc1) {
    int i = blockIdx.x * 256 + threadIdx.x;
    if (i < 32768) {
        hc0[i] = h0[i];
        cc0[i] = c0[i];
        hc1[i] = h0[32768 + i];
        cc1[i] = c0[32768 + i];
    }
}

// ---------------- chunk GEMM: out[outr][n] = sum_k A[arow][k]*Bw[n][k] + bias[n]
// 4096 rows (one chunk: 64 t x 64 b), 2048 cols. Bw: [2048][K].
// mode 0 (layer-0): r = b*TC + t  -> arow = b*512 + t0 + t, outr = t*64 + b
// mode 1 (layer-1): arow = r (rows already [t][b]), outr = r
template <int K>
__global__ __launch_bounds__(256) void gemm_xw(
    const float* __restrict__ A, const float* __restrict__ Bw,
    const float* __restrict__ bias, float* __restrict__ out,
    const int mode, const int t0) {
    __shared__ float As[16][128];
    __shared__ float Bs[16][128];
    const int tid = threadIdx.x;
    const int bm = blockIdx.y, bn = blockIdx.x;
    const int lrow = tid >> 1;      // 0..127
    const int lk0 = (tid & 1) * 8;  // 0 or 8
    const int grow = bm * 128 + lrow;
    const int arow = mode ? grow : ((grow >> 6) * 512 + t0 + (grow & 63));
    const float* Ap = A + (size_t)arow * K + lk0;
    const float* Bp = Bw + (size_t)(bn * 128 + lrow) * K + lk0;
    const int ty = tid >> 4, tx = tid & 15;

    float acc[8][8];
#pragma unroll
    for (int i = 0; i < 8; ++i)
#pragma unroll
        for (int j = 0; j < 8; ++j) acc[i][j] = 0.f;

    float4 pa0 = *(const float4*)(Ap);
    float4 pa1 = *(const float4*)(Ap + 4);
    float4 pb0 = *(const float4*)(Bp);
    float4 pb1 = *(const float4*)(Bp + 4);

    const int NT = K / 16;
    for (int ktile = 0; ktile < NT; ++ktile) {
#pragma unroll
        for (int c = 0; c < 4; ++c) {
            As[lk0 + c][lrow] = ((float*)&pa0)[c];
            As[lk0 + 4 + c][lrow] = ((float*)&pa1)[c];
            Bs[lk0 + c][lrow] = ((float*)&pb0)[c];
            Bs[lk0 + 4 + c][lrow] = ((float*)&pb1)[c];
        }
        __syncthreads();
        if (ktile + 1 < NT) {
            const float* Apn = Ap + (ktile + 1) * 16;
            const float* Bpn = Bp + (ktile + 1) * 16;
            pa0 = *(const float4*)(Apn);
            pa1 = *(const float4*)(Apn + 4);
            pb0 = *(const float4*)(Bpn);
            pb1 = *(const float4*)(Bpn + 4);
        }
#pragma unroll
        for (int kk = 0; kk < 16; ++kk) {
            const float4 a0 = *(const float4*)&As[kk][ty * 8];
            const float4 a1 = *(const float4*)&As[kk][ty * 8 + 4];
            const float4 b0 = *(const float4*)&Bs[kk][tx * 8];
            const float4 b1 = *(const float4*)&Bs[kk][tx * 8 + 4];
            const float av[8] = {a0.x, a0.y, a0.z, a0.w, a1.x, a1.y, a1.z, a1.w};
            const float bv[8] = {b0.x, b0.y, b0.z, b0.w, b1.x, b1.y, b1.z, b1.w};
#pragma unroll
            for (int i = 0; i < 8; ++i)
#pragma unroll
                for (int j = 0; j < 8; ++j) acc[i][j] = fmaf(av[i], bv[j], acc[i][j]);
        }
        __syncthreads();
    }

    const int col0 = bn * 128 + tx * 8;
    const float4 bv0 = *(const float4*)&bias[col0];
    const float4 bv1 = *(const float4*)&bias[col0 + 4];
    const float bb[8] = {bv0.x, bv0.y, bv0.z, bv0.w, bv1.x, bv1.y, bv1.z, bv1.w};
#pragma unroll
    for (int i = 0; i < 8; ++i) {
        int gr = bm * 128 + ty * 8 + i;
        int outr = mode ? gr : ((gr & 63) * 64 + (gr >> 6));
        float* op = out + (size_t)outr * 2048 + col0;
#pragma unroll
        for (int j = 0; j < 8; ++j) op[j] = acc[i][j] + bb[j];
    }
}

// ---------------- persistent LSTM recurrence over one TC chunk ----------------
// Grid = 512 WGs x 256 threads, 2 WGs/CU (only 16 KB LDS each; co-resident WGs
// belong to different sync groups -> their compute hides each other's waits).
// WG: js = bid>>3 (8 j-units), bb = bid&7 (8 batches). Sync group = 64 WGs
// sharing bb. W_hh slice lives in REGISTERS (time-invariant, 16 float4/thread).
// Thread (jt, kt): j = js*8+jt, k in [kt*16, kt*16+16). 32 accs [4g][8b];
// 31-shfl merge-exchange -> lane kt owns (g=kt>>3, b=kt&7); 4 width-32
// shuffles gather the gates; update computed redundantly per g-replica.
__global__ __launch_bounds__(256, 2) void lstm_rec(
    const float* __restrict__ xW,   // [TC][64][2048]
    const float* __restrict__ Whh,  // [2048][512]
    float* hcar, float* ccar,
    float* hbuf, const int full_seq, unsigned* flags, const int fbase) {
    __shared__ float h4[8 * 512];  // 16 KB, f4-slot XOR swizzled
    const int tid = threadIdx.x;
    const int js = blockIdx.x >> 3;  // 0..63
    const int bb = blockIdx.x & 7;   // XCD-aligned batch group
    const int jt = tid >> 5, kt = tid & 31;
    const int j_cell = js * 8 + jt;
    const int b_own = kt & 7;
    const int g_own = kt >> 3;
    const int b_cell = bb * 8 + b_own;
    unsigned* gflags = flags + bb * NGW;

    // ---- W_hh slice into registers (once): Wv[g][q] = W[g*512+j][kt*16+q*4 ..+3]
    float4 Wv[4][4];
#pragma unroll
    for (int g = 0; g < 4; ++g) {
        const float* wp = Whh + (size_t)(g * 512 + j_cell) * 512 + kt * 16;
#pragma unroll
        for (int q = 0; q < 4; ++q) Wv[g][q] = *(const float4*)(wp + q * 4);
    }

    float c = ccar[b_cell * 512 + j_cell];
    if (g_own == 0)  // publish slot-0 h
        st_agent_f32(&hbuf[b_cell * 512 + j_cell], hcar[b_cell * 512 + j_cell]);

    // ---- barrier 0: publish slot-0 h ----
    __syncthreads();  // drains sc1 stores
    if (tid == 0) st_agent_u32(&gflags[js], (unsigned)(fbase + 1));
    if (tid < 64) {
        const unsigned tgt = (unsigned)(fbase + 1);
        int guard = 0;
        for (;;) {
            unsigned v = ld_agent_u32(&gflags[tid & (NGW - 1)]);
            if (__all((int)(v >= tgt))) break;
            __builtin_amdgcn_s_sleep(2);
            if (++guard > (1 << 18)) break;  // failsafe -> visible absmax failure
        }
    }
    __syncthreads();

    for (int t = 0; t < TC; ++t) {
        const int rd = full_seq ? t : (t & 1);
        const int wr = full_seq ? (t + 1) : ((t + 1) & 1);
        const float* hrd = hbuf + (size_t)rd * 32768;

        // stage h tile [8b][512k] into LDS via sc1 8B loads (f4-slot swizzled)
#pragma unroll
        for (int i = 0; i < 8; ++i) {
            int fid = tid + i * 256;  // 0..2047
            int b = fid >> 8, k2 = fid & 255;
            unsigned long long v =
                ld_agent_u64((const unsigned long long*)&hrd[(bb * 8 + b) * 512 + k2 * 2]);
            int slot4 = b * 128 + (k2 >> 1);
            int phys = slot4 ^ ((slot4 >> 4) & 7);
            *(unsigned long long*)&h4[phys * 4 + (k2 & 1) * 2] = v;
        }
        __syncthreads();

        // own-gate xW pre-activation (issued now, consumed after reduction ->
        // HBM/LLC latency hides under the MAC loop; off the publish path)
        const float xw = xW[(size_t)t * 131072 + b_cell * 2048 + g_own * 512 + j_cell];

        // ---- MACs: acc[g*8+b] += Wv[g][q] . h[b][kt*16+q*4 ..] ----
        float acc[32];
#pragma unroll
        for (int v = 0; v < 32; ++v) acc[v] = 0.f;
#pragma unroll
        for (int q = 0; q < 4; ++q) {
#pragma unroll
            for (int b = 0; b < 8; ++b) {
                const int slot = b * 128 + kt * 4 + q;
                const float4 hv = *(const float4*)&h4[(slot ^ ((slot >> 4) & 7)) * 4];
#pragma unroll
                for (int g = 0; g < 4; ++g) {
                    acc[g * 8 + b] = fmaf(Wv[g][q].x, hv.x, acc[g * 8 + b]);
                    acc[g * 8 + b] = fmaf(Wv[g][q].y, hv.y, acc[g * 8 + b]);
                    acc[g * 8 + b] = fmaf(Wv[g][q].z, hv.z, acc[g * 8 + b]);
                    acc[g * 8 + b] = fmaf(Wv[g][q].w, hv.w, acc[g * 8 + b]);
                }
            }
        }

        // ---- 5-stage merge-exchange over kt; lane kt ends owning v = kt ----
        float v16[16];
#pragma unroll
        for (int i = 0; i < 16; ++i) {
            float hi = acc[i + 16], lo = acc[i];
            float keep = (kt & 16) ? hi : lo;
            float send = (kt & 16) ? lo : hi;
            v16[i] = keep + __shfl_xor(send, 16);
        }
        float v8[8];
#pragma unroll
        for (int i = 0; i < 8; ++i) {
            float hi = v16[i + 8], lo = v16[i];
            float keep = (kt & 8) ? hi : lo;
            float send = (kt & 8) ? lo : hi;
            v8[i] = keep + __shfl_xor(send, 8);
        }
        float v4a[4];
#pragma unroll
        for (int i = 0; i < 4; ++i) {
            float hi = v8[i + 4], lo = v8[i];
            float keep = (kt & 4) ? hi : lo;
            float send = (kt & 4) ? lo : hi;
            v4a[i] = keep + __shfl_xor(send, 4);
        }
        float v2a[2];
#pragma unroll
        for (int i = 0; i < 2; ++i) {
            float hi = v4a[i + 2], lo = v4a[i];
            float keep = (kt & 2) ? hi : lo;
            float send = (kt & 2) ? lo : hi;
            v2a[i] = keep + __shfl_xor(send, 2);
        }
        float s;
        {
            float hi = v2a[1], lo = v2a[0];
            float keep = (kt & 1) ? hi : lo;
            float send = (kt & 1) ? lo : hi;
            s = keep + __shfl_xor(send, 1);
        }

        // gather the 4 gate pre-acts for (j_cell, b_own) — width-32 segments
        const float sfull = s + xw;
        const float p0 = __shfl(sfull, 0 + b_own, 32);
        const float p1 = __shfl(sfull, 8 + b_own, 32);
        const float p2 = __shfl(sfull, 16 + b_own, 32);
        const float p3 = __shfl(sfull, 24 + b_own, 32);

        const float gi = sigmoidf_(p0);
        const float gf = sigmoidf_(p1);
        const float gg = tanhf_(p2);
        const float go = sigmoidf_(p3);
        c = gf * c + gi * gg;  // identical across the 4 g-replica lanes
        const float hn = go * tanhf_(c);
        if (g_own == 0) {
            st_agent_f32(&hbuf[(size_t)wr * 32768 + b_cell * 512 + j_cell], hn);
            if (t == TC - 1) {  // carries for next chunk (cross-dispatch)
                hcar[b_cell * 512 + j_cell] = hn;
                ccar[b_cell * 512 + j_cell] = c;
            }
        }

        // ---- publish h(t+1) + wait for group (skip after last step) ----
        if (t < TC - 1) {
            __syncthreads();  // drains sc1 h stores
            if (tid == 0) st_agent_u32(&gflags[js], (unsigned)(fbase + t + 2));
            if (tid < 64) {
                const unsigned tgt = (unsigned)(fbase + t + 2);
                int guard = 0;
                for (;;) {
                    unsigned v = ld_agent_u32(&gflags[tid & (NGW - 1)]);
                    if (__all((int)(v >= tgt))) break;
                    __builtin_amdgcn_s_sleep(2);
                    if (++guard > (1 << 18)) break;  // failsafe
                }
            }
            __syncthreads();
        }
    }
}

// ---------------- FC head ----------------
__global__ __launch_bounds__(256) void fc_kernel(
    const float* __restrict__ h, const float* __restrict__ Wfc,
    const float* __restrict__ bfc, float* __restrict__ out) {
    int gid = blockIdx.x * 256 + threadIdx.x;  // 0..8191
    int b = gid >> 7, cc = gid & 127;
    const float* hr = h + b * 512;
    const float* wr = Wfc + cc * 512;
    float s = 0.f;
#pragma unroll 4
    for (int k = 0; k < 512; k += 4) {
        float4 hv = *(const float4*)(hr + k);
        float4 wv = *(const float4*)(wr + k);
        s += hv.x * wv.x + hv.y * wv.y + hv.z * wv.z + hv.w * wv.w;
    }
    out[gid] = s + bfc[cc];
}

// ---------------- launch ----------------
extern "C" void kernel_launch(void* const* d_in, const int* in_sizes, int n_in,
                              void* d_out, int out_size, void* d_ws, size_t ws_size,
                              hipStream_t stream) {
    const float* x = (const float*)d_in[0];
    const float* h0 = (const float*)d_in[1];
    const float* c0 = (const float*)d_in[2];
    const float* Wih0 = (const float*)d_in[3];
    const float* Whh0 = (const float*)d_in[4];
    const float* bih0 = (const float*)d_in[5];
    const float* bhh0 = (const float*)d_in[6];
    const float* Wih1 = (const float*)d_in[7];
    const float* Whh1 = (const float*)d_in[8];
    const float* bih1 = (const float*)d_in[9];
    const float* bhh1 = (const float*)d_in[10];
    const float* Wfc = (const float*)d_in[11];
    const float* bfc = (const float*)d_in[12];

    // workspace layout (~43 MB total)
    char* ws = (char*)d_ws;
    size_t off = 0;
    float* xWc = (float*)(ws + off); off += (size_t)TC * 64 * 2048 * 4;      // 33,554,432
    float* hseqc = (float*)(ws + off); off += (size_t)(TC + 1) * 32768 * 4;  //  8,519,680
    float* hpp = (float*)(ws + off); off += 2 * 32768 * 4;                   //    262,144
    float* hcar0 = (float*)(ws + off); off += 32768 * 4;
    float* ccar0 = (float*)(ws + off); off += 32768 * 4;
    float* hcar1 = (float*)(ws + off); off += 32768 * 4;
    float* ccar1 = (float*)(ws + off); off += 32768 * 4;
    float* bs0 = (float*)(ws + off); off += 2048 * 4;
    float* bs1 = (float*)(ws + off); off += 2048 * 4;
    unsigned* flagsA = (unsigned*)(ws + off); off += 8 * NGW * 4;  // layer-0 flags
    unsigned* flagsB = (unsigned*)(ws + off); off += 8 * NGW * 4;  // layer-1 flags

    prep_bias<<<8, 256, 0, stream>>>(bih0, bhh0, bih1, bhh1, bs0, bs1);
    init_carry<<<128, 256, 0, stream>>>(h0, c0, hcar0, ccar0, hcar1, ccar1);
    hipMemsetAsync(flagsA, 0, 2 * 8 * NGW * 4, stream);

    const dim3 gg(16, 32);
    for (int k = 0; k < NCHUNK; ++k) {
        // layer-0 input GEMM for chunk k: xWc[t][b][2048]
        gemm_xw<256><<<gg, 256, 0, stream>>>(x, Wih0, bs0, xWc, 0, k * TC);
        // layer-0 recurrence over chunk; writes hseqc slots 1..TC
        lstm_rec<<<512, 256, 0, stream>>>(xWc, Whh0, hcar0, ccar0, hseqc, 1, flagsA, k * TC);
        // layer-1 input GEMM from hseqc slots 1..TC (rows already [t][b])
        gemm_xw<512><<<gg, 256, 0, stream>>>(hseqc + 32768, Wih1, bs1, xWc, 1, 0);
        // layer-1 recurrence (ping-pong h)
        lstm_rec<<<512, 256, 0, stream>>>(xWc, Whh1, hcar1, ccar1, hpp, 0, flagsB, k * TC);
    }
    // FC on final layer-1 hidden state (carry buffer)
    fc_kernel<<<32, 256, 0, stream>>>(hcar1, Wfc, bfc, (float*)d_out);
}